// Round 1
// baseline (787.253 us; speedup 1.0000x reference)
//
#include <hip/hip_runtime.h>
#include <hip/hip_fp16.h>
#include <math.h>

// Problem constants
#define S 2048
#define D 64
#define BH 32          // B*H = 2*16
#define TILE 64
#define NT (S / TILE)  // 32
#define SP1 (S + 1)    // 2049

typedef _Float16 f16;
typedef f16 f16x8 __attribute__((ext_vector_type(8)));
typedef f16 f16x4 __attribute__((ext_vector_type(4)));
typedef float f32x4 __attribute__((ext_vector_type(4)));

#define LDS_PITCH 72   // halfs per row: 64 + 8 pad -> row stride 144 B (16B-aligned, 2-way-max bank alias = free)

// ---------------------------------------------------------------------------
// Phase 1: rinv[bh*S + j] = 1/||k_j||   (one wave per row, lane d holds k[j][d])
// ---------------------------------------------------------------------------
__global__ __launch_bounds__(256) void knorm_kernel(const float* __restrict__ k,
                                                    float* __restrict__ rinv) {
    int row  = (blockIdx.x * 256 + threadIdx.x) >> 6;
    int lane = threadIdx.x & 63;
    float v = k[(size_t)row * D + lane];
    float s = v * v;
    #pragma unroll
    for (int off = 32; off; off >>= 1) s += __shfl_xor(s, off);
    if (lane == 0) rinv[row] = 1.0f / sqrtf(s);
}

// ---------------------------------------------------------------------------
// Phase 2: row denominators.
// Block = (it, bh): 64 q-rows; loop over causal k-tiles, MFMA f16 scores,
// accumulate sum of exp(score * rinv_j). inv_l = 1/(sum + (S-1-i) + exp(sink_i)).
// MFMA 16x16x32 f16. C/D: col=lane&15, row=(lane>>4)*4+reg.
// A/B frag: lane holds row (lane&15), k-range quad*8..+7 (8 contiguous halfs).
// ---------------------------------------------------------------------------
__global__ __launch_bounds__(256) void rowsum_kernel(
    const float* __restrict__ q, const float* __restrict__ k,
    const float* __restrict__ sinks, const float* __restrict__ rinv,
    float* __restrict__ inv_l)
{
    __shared__ __align__(16) f16 qs[TILE * LDS_PITCH];
    __shared__ __align__(16) f16 ks[TILE * LDS_PITCH];

    const int it = blockIdx.x;
    const int bh = blockIdx.y;
    const int i0 = it * TILE;
    const int tid  = threadIdx.x;
    const int lane = tid & 63;
    const int w    = tid >> 6;
    const int m    = lane & 15;
    const int quad = lane >> 4;

    const float* qbase = q + (size_t)bh * S * D;
    const float* kbase = k + (size_t)bh * S * D;

    // stage q tile (fp32 -> f16)
    {
        int r  = tid >> 4;
        int c4 = (tid & 15) * 4;
        #pragma unroll
        for (int rb = 0; rb < 4; rb++) {
            int row = rb * 16 + r;
            float4 v = *(const float4*)(qbase + (size_t)(i0 + row) * D + c4);
            f16x4 hv; hv[0] = (f16)v.x; hv[1] = (f16)v.y; hv[2] = (f16)v.z; hv[3] = (f16)v.w;
            *(f16x4*)&qs[row * LDS_PITCH + c4] = hv;
        }
    }
    __syncthreads();

    // A fragments (q rows w*16..w*16+15), both K=32 halves of D=64
    f16x8 a0 = *(const f16x8*)&qs[(w * 16 + m) * LDS_PITCH + 0  + quad * 8];
    f16x8 a1 = *(const f16x8*)&qs[(w * 16 + m) * LDS_PITCH + 32 + quad * 8];

    float rowsum[4] = {0.f, 0.f, 0.f, 0.f};
    const int ib = i0 + w * 16 + quad * 4;   // first of 4 rows this lane accumulates

    for (int jt = 0; jt <= it; jt++) {
        const int j0 = jt * TILE;
        __syncthreads();   // prior iter done reading ks
        {
            int r  = tid >> 4;
            int c4 = (tid & 15) * 4;
            #pragma unroll
            for (int rb = 0; rb < 4; rb++) {
                int row = rb * 16 + r;
                float4 v = *(const float4*)(kbase + (size_t)(j0 + row) * D + c4);
                f16x4 hv; hv[0] = (f16)v.x; hv[1] = (f16)v.y; hv[2] = (f16)v.z; hv[3] = (f16)v.w;
                *(f16x4*)&ks[row * LDS_PITCH + c4] = hv;
            }
        }
        __syncthreads();

        const bool diag = (jt == it);
        #pragma unroll
        for (int st = 0; st < 4; st++) {
            f16x8 b0 = *(const f16x8*)&ks[(st * 16 + m) * LDS_PITCH + 0  + quad * 8];
            f16x8 b1 = *(const f16x8*)&ks[(st * 16 + m) * LDS_PITCH + 32 + quad * 8];
            f32x4 acc = {0.f, 0.f, 0.f, 0.f};
            acc = __builtin_amdgcn_mfma_f32_16x16x32_f16(a0, b0, acc, 0, 0, 0);
            acc = __builtin_amdgcn_mfma_f32_16x16x32_f16(a1, b1, acc, 0, 0, 0);
            const int j = j0 + st * 16 + m;
            const float rj = rinv[bh * S + j];
            #pragma unroll
            for (int r = 0; r < 4; r++) {
                float e = __expf(acc[r] * rj);
                if (diag && j > ib + r) e = 0.0f;   // upper-tri handled in closed form
                rowsum[r] += e;
            }
        }
    }

    // reduce across the 16 lanes of each quad (columns of the score tile)
    #pragma unroll
    for (int off = 1; off < 16; off <<= 1)
        #pragma unroll
        for (int r = 0; r < 4; r++) rowsum[r] += __shfl_xor(rowsum[r], off);

    if (m == 0) {
        #pragma unroll
        for (int r = 0; r < 4; r++) {
            int i = ib + r;
            float l = rowsum[r] + (float)(S - 1 - i) + __expf(sinks[bh * S + i]);
            inv_l[bh * S + i] = 1.0f / l;
        }
    }
}

// ---------------------------------------------------------------------------
// Phase 3: output tiles.
//  jt > it : pure broadcast of inv_l (no compute)
//  jt <= it: recompute scores via MFMA, write exp(w)*inv_l (diag: masked)
// ---------------------------------------------------------------------------
__global__ __launch_bounds__(256) void out_kernel(
    const float* __restrict__ q, const float* __restrict__ k,
    const float* __restrict__ rinv, const float* __restrict__ inv_l,
    float* __restrict__ out)
{
    const int jt = blockIdx.x;
    const int it = blockIdx.y;
    const int bh = blockIdx.z;
    const int i0 = it * TILE, j0 = jt * TILE;
    const int tid = threadIdx.x;
    float* obase = out + (size_t)bh * S * SP1;

    if (jt > it) {
        // upper triangle: out = 1/l_i, coalesced 256B stores per wave
        const int rb = tid >> 6;
        const int c  = tid & 63;
        #pragma unroll
        for (int r = 0; r < 16; r++) {
            int i = i0 + rb * 16 + r;
            obase[(size_t)i * SP1 + j0 + c] = inv_l[bh * S + i];
        }
        return;
    }

    __shared__ __align__(16) f16 qs[TILE * LDS_PITCH];
    __shared__ __align__(16) f16 ks[TILE * LDS_PITCH];

    const int lane = tid & 63;
    const int w    = tid >> 6;
    const int m    = lane & 15;
    const int quad = lane >> 4;

    const float* qbase = q + (size_t)bh * S * D;
    const float* kbase = k + (size_t)bh * S * D;

    {
        int r  = tid >> 4;
        int c4 = (tid & 15) * 4;
        #pragma unroll
        for (int rb = 0; rb < 4; rb++) {
            int row = rb * 16 + r;
            float4 vq = *(const float4*)(qbase + (size_t)(i0 + row) * D + c4);
            f16x4 hq; hq[0] = (f16)vq.x; hq[1] = (f16)vq.y; hq[2] = (f16)vq.z; hq[3] = (f16)vq.w;
            *(f16x4*)&qs[row * LDS_PITCH + c4] = hq;
            float4 vk = *(const float4*)(kbase + (size_t)(j0 + row) * D + c4);
            f16x4 hk; hk[0] = (f16)vk.x; hk[1] = (f16)vk.y; hk[2] = (f16)vk.z; hk[3] = (f16)vk.w;
            *(f16x4*)&ks[row * LDS_PITCH + c4] = hk;
        }
    }
    __syncthreads();

    f16x8 a0 = *(const f16x8*)&qs[(w * 16 + m) * LDS_PITCH + 0  + quad * 8];
    f16x8 a1 = *(const f16x8*)&qs[(w * 16 + m) * LDS_PITCH + 32 + quad * 8];

    const int ib = i0 + w * 16 + quad * 4;
    float il[4];
    #pragma unroll
    for (int r = 0; r < 4; r++) il[r] = inv_l[bh * S + ib + r];

    const bool diag = (jt == it);
    #pragma unroll
    for (int st = 0; st < 4; st++) {
        f16x8 b0 = *(const f16x8*)&ks[(st * 16 + m) * LDS_PITCH + 0  + quad * 8];
        f16x8 b1 = *(const f16x8*)&ks[(st * 16 + m) * LDS_PITCH + 32 + quad * 8];
        f32x4 acc = {0.f, 0.f, 0.f, 0.f};
        acc = __builtin_amdgcn_mfma_f32_16x16x32_f16(a0, b0, acc, 0, 0, 0);
        acc = __builtin_amdgcn_mfma_f32_16x16x32_f16(a1, b1, acc, 0, 0, 0);
        const int j = j0 + st * 16 + m;
        const float rj = rinv[bh * S + j];
        #pragma unroll
        for (int r = 0; r < 4; r++) {
            float val = __expf(acc[r] * rj) * il[r];
            if (diag && j > ib + r) val = il[r];   // exp(0)/l
            obase[(size_t)(ib + r) * SP1 + j] = val;
        }
    }
}

// ---------------------------------------------------------------------------
// Phase 4: sink column j = S
// ---------------------------------------------------------------------------
__global__ __launch_bounds__(256) void sink_kernel(const float* __restrict__ sinks,
                                                   const float* __restrict__ inv_l,
                                                   float* __restrict__ out) {
    int t = blockIdx.x * 256 + threadIdx.x;
    out[(size_t)t * SP1 + S] = __expf(sinks[t]) * inv_l[t];
}

// ---------------------------------------------------------------------------
extern "C" void kernel_launch(void* const* d_in, const int* in_sizes, int n_in,
                              void* d_out, int out_size, void* d_ws, size_t ws_size,
                              hipStream_t stream) {
    const float* q     = (const float*)d_in[0];
    const float* k     = (const float*)d_in[1];
    const float* sinks = (const float*)d_in[2];
    float* out = (float*)d_out;

    float* rinv  = (float*)d_ws;          // BH*S floats
    float* inv_l = rinv + BH * S;         // BH*S floats

    knorm_kernel<<<dim3(BH * S / 4), 256, 0, stream>>>(k, rinv);
    rowsum_kernel<<<dim3(NT, BH), 256, 0, stream>>>(q, k, sinks, rinv, inv_l);
    out_kernel<<<dim3(NT, NT, BH), 256, 0, stream>>>(q, k, rinv, inv_l, out);
    sink_kernel<<<dim3(BH * S / 256), 256, 0, stream>>>(sinks, inv_l, out);
}